// Round 14
// baseline (153.590 us; speedup 1.0000x reference)
//
#include <hip/hip_runtime.h>
#include <math.h>

#define NCOL 8192
#define BT   256
#define NCH  32    // float4 chunks per row (64 lanes x 4 floats x 32 = 8192)

// exact double constants
#define MZM_LOSS_D 0.8912509381337456   // 10^-0.05
#define YB_LOSS_D  0.9332543007969910   // 10^-0.03
#define MRR_LOSS_D 0.8912509381337456   // 10^-0.05

// Markstein: dst = rint(f32div(a, inorm) * 255), exact IEEE f32 division
#define QF(dst, a_) do {                                   \
    const float a__  = (a_);                               \
    const float q0__ = a__ * y;                            \
    const float r__  = fmaf(-inorm, q0__, a__);            \
    (dst) = rintf(fmaf(r__, y, q0__) * 255.f);             \
} while (0)

// emit chunk k: conv + D/T accumulate for the 4 owned elems (window via shfl)
#define EMIT(NQ0, NQ1, EDGEL, EDGER) do {                                     \
    float Qm2 = __shfl_up(q2, 1);                                             \
    float Qm1 = __shfl_up(q3, 1);                                             \
    if (lane == 0) { Qm2 = blq2; Qm1 = blq3; }                                \
    float Qp1 = __shfl_down(q0, 1);                                           \
    float Qp2 = __shfl_down(q1, 1);                                           \
    const float nb0 = __shfl((NQ0), 0);                                       \
    const float nb1 = __shfl((NQ1), 0);                                       \
    if (lane == 63) { Qp1 = nb0; Qp2 = nb1; }                                 \
    const float cv0 = fmaf(0.0025f, Qm2 + q2, fmaf(0.01f, Qm1 + q1, q0));     \
    const float cv1 = fmaf(0.0025f, Qm1 + q3, fmaf(0.01f, q0  + q2, q1));     \
    const float cv2 = fmaf(0.0025f, q0 + Qp1, fmaf(0.01f, q1  + q3, q2));     \
    const float cv3 = fmaf(0.0025f, q1 + Qp2, fmaf(0.01f, q2 + Qp1, q3));     \
    D0 = fmaf(cv0, e0, D0); T0 = fmaf(cv0, fabsf(e0), T0);                    \
    D1 = fmaf(cv1, e1, D1); T1 = fmaf(cv1, fabsf(e1), T1);                    \
    D2 = fmaf(cv2, e2, D2); T2 = fmaf(cv2, fabsf(e2), T2);                    \
    D3 = fmaf(cv3, e3, D3); T3 = fmaf(cv3, fabsf(e3), T3);                    \
    if ((EDGEL) && lane == 0) {     /* row elems 0 (DE0), 1 (DE1) */          \
        cD += DE0 * (double)(cv0 * e0) + DE1 * (double)(cv1 * e1);            \
        cT += DE0 * (double)(cv0 * fabsf(e0)) + DE1 * (double)(cv1 * fabsf(e1)); \
    }                                                                         \
    if ((EDGER) && lane == 63) {    /* row elems N-2 (DE1), N-1 (DE0) */      \
        cD += DE1 * (double)(cv2 * e2) + DE0 * (double)(cv3 * e3);            \
        cT += DE1 * (double)(cv2 * fabsf(e2)) + DE0 * (double)(cv3 * fabsf(e3)); \
    }                                                                         \
} while (0)

__global__ __launch_bounds__(BT)
void odp_main(const float* __restrict__ x, const float* __restrict__ w,
              const float* __restrict__ ntp, const float* __restrict__ nsp,
              const float* __restrict__ ntn, const float* __restrict__ nsn,
              float* __restrict__ out)
{
    const int lane = threadIdx.x & 63;
    const int row  = blockIdx.x * (BT / 64) + (threadIdx.x >> 6);

    const float4* __restrict__ xr4 = (const float4*)(x + (size_t)row * NCOL);
    const float4* __restrict__ w4  = (const float4*)w;

    const float vntp = ntp[row], vnsp = nsp[row];
    const float vntn = ntn[row], vnsn = nsn[row];

    // ---- pass 1: row max|x| (lane-consecutive float4 = fully coalesced) ----
    float m0 = 0.f, m1 = 0.f, m2 = 0.f, m3 = 0.f;
#pragma unroll 8
    for (int k = 0; k < NCH; ++k) {
        const float4 v = xr4[(k << 6) + lane];
        m0 = fmaxf(m0, fabsf(v.x)); m1 = fmaxf(m1, fabsf(v.y));
        m2 = fmaxf(m2, fabsf(v.z)); m3 = fmaxf(m3, fabsf(v.w));
    }
    float mx = fmaxf(fmaxf(m0, m1), fmaxf(m2, m3));
#pragma unroll
    for (int off = 1; off < 64; off <<= 1)
        mx = fmaxf(mx, __shfl_xor(mx, off));          // butterfly: no barrier
    const float inorm = (mx <= 1e-9f) ? 1.f : mx;
    const double inv_d = 1.0 / (double)inorm;         // correctly-rounded f32 recip seed
    const float  y     = (float)inv_d;

    asm volatile("" ::: "memory");   // block x-load CSE across passes (keep VGPR low)

    // ---- pass 2: re-stream row (L3-hot), quantize, conv via shfl, accumulate ----
    float D0=0.f,D1=0.f,D2=0.f,D3=0.f, T0=0.f,T1=0.f,T2=0.f,T3=0.f;
    double cD = 0.0, cT = 0.0;
    const double DE0 = -((double)0.01f + (double)0.0025f);  // elems 0, N-1
    const double DE1 = -((double)0.0025f);                  // elems 1, N-2

    // chunk 0
    float4 xv = xr4[lane];
    float4 wv = w4[lane];
    float mw = fmaxf(fmaxf(fabsf(wv.x), fabsf(wv.y)),
                     fmaxf(fabsf(wv.z), fabsf(wv.w)));
    float q0, q1, q2, q3;
    QF(q0, fabsf(xv.x)); QF(q1, fabsf(xv.y));
    QF(q2, fabsf(xv.z)); QF(q3, fabsf(xv.w));
    float e0 = (xv.x > 0.f) ? wv.x : -wv.x;
    float e1 = (xv.y > 0.f) ? wv.y : -wv.y;
    float e2 = (xv.z > 0.f) ? wv.z : -wv.z;
    float e3 = (xv.w > 0.f) ? wv.w : -wv.w;
    float blq2 = 0.f, blq3 = 0.f;   // prev-chunk lane63 q2,q3 (row start: zero pad)

#pragma unroll 4
    for (int k = 0; k < NCH - 1; ++k) {
        // lookahead: load + quantize chunk k+1
        xv = xr4[((k + 1) << 6) + lane];
        wv = w4 [((k + 1) << 6) + lane];
        mw = fmaxf(mw, fmaxf(fmaxf(fabsf(wv.x), fabsf(wv.y)),
                             fmaxf(fabsf(wv.z), fabsf(wv.w))));
        float nq0, nq1, nq2, nq3;
        QF(nq0, fabsf(xv.x)); QF(nq1, fabsf(xv.y));
        QF(nq2, fabsf(xv.z)); QF(nq3, fabsf(xv.w));
        const float ne0 = (xv.x > 0.f) ? wv.x : -wv.x;
        const float ne1 = (xv.y > 0.f) ? wv.y : -wv.y;
        const float ne2 = (xv.z > 0.f) ? wv.z : -wv.z;
        const float ne3 = (xv.w > 0.f) ? wv.w : -wv.w;

        EMIT(nq0, nq1, (k == 0), false);

        blq2 = __shfl(q2, 63);        // carry for next emission's lane 0
        blq3 = __shfl(q3, 63);
        q0 = nq0; q1 = nq1; q2 = nq2; q3 = nq3;
        e0 = ne0; e1 = ne1; e2 = ne2; e3 = ne3;
    }
    {   // final chunk: right neighbor = zero pad (conv 'SAME')
        const float z = 0.f;
        EMIT(z, z, false, true);
    }

    // ---- wave reduce (no barrier): D f64, T f32, max|w| ----
    double accD = ((double)D0 + (double)D1) + ((double)D2 + (double)D3);
    float  accT = (T0 + T1) + (T2 + T3);
#pragma unroll
    for (int off = 32; off; off >>= 1) {
        accD += __shfl_down(accD, off);
        accT += __shfl_down(accT, off);
        mw    = fmaxf(mw, __shfl_down(mw, off));
    }
    const double cDs = __shfl(cD, 0) + __shfl(cD, 63);
    const double cTs = __shfl(cT, 0) + __shfl(cT, 63);

    if (lane == 0) {
        const float wnorm = (mw <= 1e-9f) ? 1.f : mw;
        const double E_MID = 1.0 + 2.0 * (double)0.01f + 2.0 * (double)0.0025f;
        const double D = accD * E_MID + cDs;
        const double T = ((double)accT) * E_MID + cTs;

        const double Kd = (10.0 / 255.0) * (YB_LOSS_D * MZM_LOSS_D) / (double)wnorm;
        const double ps = (T + D) * 0.5 * Kd * MRR_LOSS_D;
        const double ns = (T - D) * 0.5 * Kd * MRR_LOSS_D;

        const float thermal_f = 3.3135576e-12f;   // f32(4*kB*T*Hz/R)
        const float shot_f    = 3.204353268e-9f;  // f32(2*qE*Hz)

        double tp_ = ps + 1e-12 + (double)(vntp * thermal_f);
        tp_ *= (double)(1.0f + vnsp * shot_f);    // == *1.0 in f32, faithful
        double tn_ = ns + 1e-12 + (double)(vntn * thermal_f);
        tn_ *= (double)(1.0f + vnsn * shot_f);

        const double cur = tp_ - tn_;
        double v = fabs(cur * 100.0);
        v = fmin(v, 1.0);
        const double va  = rint(v * 255.0) * (1.0 / 255.0);
        const double sgn = (cur >= 0.0) ? 1.0 : -1.0;
        const double scale = (double)wnorm /
            (10.0 * 100.0 * MRR_LOSS_D * YB_LOSS_D * MZM_LOSS_D);
        out[row] = (float)(va * sgn * scale * (double)inorm);
    }
}

extern "C" void kernel_launch(void* const* d_in, const int* in_sizes, int n_in,
                              void* d_out, int out_size, void* d_ws, size_t ws_size,
                              hipStream_t stream) {
    const float* x   = (const float*)d_in[0];
    const float* w   = (const float*)d_in[1];
    const float* ntp = (const float*)d_in[2];
    const float* nsp = (const float*)d_in[3];
    const float* ntn = (const float*)d_in[4];
    const float* nsn = (const float*)d_in[5];
    float* out = (float*)d_out;
    const int nblocks = out_size / (BT / 64);   // 4096 rows -> 1024 blocks
    odp_main<<<dim3(nblocks), dim3(BT), 0, stream>>>(x, w, ntp, nsp, ntn, nsn, out);
}

// Round 15
// 49.751 us; speedup vs baseline: 3.0872x; 3.0872x over previous
//
#include <hip/hip_runtime.h>
#include <math.h>

#define NCOL 8192
#define BT   256
#define NCH  32    // float4 chunks per row: 64 lanes x 32 = 2048 float4 = 8192 floats

// exact double constants
#define MZM_LOSS_D 0.8912509381337456   // 10^-0.05
#define YB_LOSS_D  0.9332543007969910   // 10^-0.03
#define MRR_LOSS_D 0.8912509381337456   // 10^-0.05

// Markstein: dst = rint(f32div(a, inorm) * 255), exact IEEE f32 division
#define QF(dst, a_) do {                                   \
    const float a__  = (a_);                               \
    const float q0__ = a__ * y;                            \
    const float r__  = fmaf(-inorm, q0__, a__);            \
    (dst) = rintf(fmaf(r__, y, q0__) * 255.f);             \
} while (0)

__global__ __launch_bounds__(BT, 6)   // cap VGPR ~85: no spills, >=6 waves/EU
void odp_main(const float* __restrict__ x, const float* __restrict__ w,
              const float* __restrict__ ntp, const float* __restrict__ nsp,
              const float* __restrict__ ntn, const float* __restrict__ nsn,
              float* __restrict__ out)
{
    const int lane = threadIdx.x & 63;
    const int row  = blockIdx.x * (BT / 64) + (threadIdx.x >> 6);

    const float*  __restrict__ xrow = x + (size_t)row * NCOL;
    const float4* __restrict__ xr4  = (const float4*)xrow;
    const float4* __restrict__ w4   = (const float4*)w;

    // ---- pass 1: row max|x|, lane-consecutive float4 (perfectly coalesced) ----
    float m0 = 0.f, m1 = 0.f, m2 = 0.f, m3 = 0.f;
#pragma unroll 4
    for (int k = 0; k < NCH; ++k) {
        const float4 v = xr4[(k << 6) + lane];
        m0 = fmaxf(m0, fabsf(v.x)); m1 = fmaxf(m1, fabsf(v.y));
        m2 = fmaxf(m2, fabsf(v.z)); m3 = fmaxf(m3, fabsf(v.w));
    }
    float mx = fmaxf(fmaxf(m0, m1), fmaxf(m2, m3));
#pragma unroll
    for (int off = 1; off < 64; off <<= 1)
        mx = fmaxf(mx, __shfl_xor(mx, off));          // butterfly: no barrier
    const float inorm = (mx <= 1e-9f) ? 1.f : mx;
    const double inv_d = 1.0 / (double)inorm;         // correctly-rounded f32 recip seed
    const float  y     = (float)inv_d;

    asm volatile("" ::: "memory");   // forbid cross-pass load CSE (keep live set small)

    // ---- pass 2: re-stream row (L3-hot), halo via direct loads, accumulate ----
    float D0=0.f,D1=0.f,D2=0.f,D3=0.f, T0=0.f,T1=0.f,T2=0.f,T3=0.f;
    float mw = 0.f;
    double cD = 0.0, cT = 0.0;
    const double DE0 = -((double)0.01f + (double)0.0025f);  // elems 0, N-1
    const double DE1 = -((double)0.0025f);                  // elems 1, N-2

#pragma unroll 2
    for (int k = 0; k < NCH; ++k) {
        const int g   = (k << 6) + lane;   // float4 index
        const int off = g << 2;            // element index of .x
        const float4 xv = xr4[g];
        const float4 wv = w4[g];
        mw = fmaxf(mw, fmaxf(fmaxf(fabsf(wv.x), fabsf(wv.y)),
                             fmaxf(fabsf(wv.z), fabsf(wv.w))));
        // halos: 2 elems left / right, clamped at row ends (dummy addr, zeroed)
        const float2 hl = *(const float2*)(xrow + ((off > 0) ? off - 2 : 0));
        const float2 hr = *(const float2*)(xrow + ((off < NCOL - 4) ? off + 4 : NCOL - 2));

        float q0, q1, q2, q3, qm2, qm1, qp1, qp2;
        QF(q0, fabsf(xv.x)); QF(q1, fabsf(xv.y));
        QF(q2, fabsf(xv.z)); QF(q3, fabsf(xv.w));
        QF(qm2, fabsf(hl.x)); QF(qm1, fabsf(hl.y));
        QF(qp1, fabsf(hr.x)); QF(qp2, fabsf(hr.y));
        if (off == 0)        { qm2 = 0.f; qm1 = 0.f; }   // conv 'SAME' zero pad
        if (off == NCOL - 4) { qp1 = 0.f; qp2 = 0.f; }

        const float cv0 = fmaf(0.0025f, qm2 + q2, fmaf(0.01f, qm1 + q1, q0));
        const float cv1 = fmaf(0.0025f, qm1 + q3, fmaf(0.01f, q0  + q2, q1));
        const float cv2 = fmaf(0.0025f, q0 + qp1, fmaf(0.01f, q1  + q3, q2));
        const float cv3 = fmaf(0.0025f, q1 + qp2, fmaf(0.01f, q2 + qp1, q3));

        const float e0 = (xv.x > 0.f) ? wv.x : -wv.x;
        const float e1 = (xv.y > 0.f) ? wv.y : -wv.y;
        const float e2 = (xv.z > 0.f) ? wv.z : -wv.z;
        const float e3 = (xv.w > 0.f) ? wv.w : -wv.w;

        D0 = fmaf(cv0, e0, D0); T0 = fmaf(cv0, fabsf(e0), T0);
        D1 = fmaf(cv1, e1, D1); T1 = fmaf(cv1, fabsf(e1), T1);
        D2 = fmaf(cv2, e2, D2); T2 = fmaf(cv2, fabsf(e2), T2);
        D3 = fmaf(cv3, e3, D3); T3 = fmaf(cv3, fabsf(e3), T3);

        if (off == 0) {            // row elems 0 (DE0), 1 (DE1)
            cD += DE0 * (double)(cv0 * e0) + DE1 * (double)(cv1 * e1);
            cT += DE0 * (double)(cv0 * fabsf(e0)) + DE1 * (double)(cv1 * fabsf(e1));
        }
        if (off == NCOL - 4) {     // row elems N-2 (DE1), N-1 (DE0)
            cD += DE1 * (double)(cv2 * e2) + DE0 * (double)(cv3 * e3);
            cT += DE1 * (double)(cv2 * fabsf(e2)) + DE0 * (double)(cv3 * fabsf(e3));
        }
    }

    // ---- wave reduce (no barrier): D f64, T f32, max|w| ----
    double accD = ((double)D0 + (double)D1) + ((double)D2 + (double)D3);
    float  accT = (T0 + T1) + (T2 + T3);
#pragma unroll
    for (int off = 32; off; off >>= 1) {
        accD += __shfl_down(accD, off);
        accT += __shfl_down(accT, off);
        mw    = fmaxf(mw, __shfl_down(mw, off));
    }
    const double cDs = __shfl(cD, 0) + __shfl(cD, 63);
    const double cTs = __shfl(cT, 0) + __shfl(cT, 63);

    if (lane == 0) {
        const float wnorm = (mw <= 1e-9f) ? 1.f : mw;
        const double E_MID = 1.0 + 2.0 * (double)0.01f + 2.0 * (double)0.0025f;
        const double D = accD * E_MID + cDs;
        const double T = ((double)accT) * E_MID + cTs;

        const double Kd = (10.0 / 255.0) * (YB_LOSS_D * MZM_LOSS_D) / (double)wnorm;
        const double ps = (T + D) * 0.5 * Kd * MRR_LOSS_D;
        const double ns = (T - D) * 0.5 * Kd * MRR_LOSS_D;

        const float thermal_f = 3.3135576e-12f;   // f32(4*kB*T*Hz/R)
        const float shot_f    = 3.204353268e-9f;  // f32(2*qE*Hz)

        double tp_ = ps + 1e-12 + (double)(ntp[row] * thermal_f);
        tp_ *= (double)(1.0f + nsp[row] * shot_f);    // == *1.0 in f32, faithful
        double tn_ = ns + 1e-12 + (double)(ntn[row] * thermal_f);
        tn_ *= (double)(1.0f + nsn[row] * shot_f);

        const double cur = tp_ - tn_;
        double v = fabs(cur * 100.0);
        v = fmin(v, 1.0);
        const double va  = rint(v * 255.0) * (1.0 / 255.0);
        const double sgn = (cur >= 0.0) ? 1.0 : -1.0;
        const double scale = (double)wnorm /
            (10.0 * 100.0 * MRR_LOSS_D * YB_LOSS_D * MZM_LOSS_D);
        out[row] = (float)(va * sgn * scale * (double)inorm);
    }
}

extern "C" void kernel_launch(void* const* d_in, const int* in_sizes, int n_in,
                              void* d_out, int out_size, void* d_ws, size_t ws_size,
                              hipStream_t stream) {
    const float* x   = (const float*)d_in[0];
    const float* w   = (const float*)d_in[1];
    const float* ntp = (const float*)d_in[2];
    const float* nsp = (const float*)d_in[3];
    const float* ntn = (const float*)d_in[4];
    const float* nsn = (const float*)d_in[5];
    float* out = (float*)d_out;
    const int nblocks = out_size / (BT / 64);   // 4096 rows -> 1024 blocks
    odp_main<<<dim3(nblocks), dim3(BT), 0, stream>>>(x, w, ntp, nsp, ntn, nsn, out);
}